// Round 10
// baseline (209.336 us; speedup 1.0000x reference)
//
#include <hip/hip_runtime.h>
#include <hip/hip_bf16.h>

// ---------------------------------------------------------------------------
// SingleLayerMoE: T=1024 tokens, H=1024, E=8 experts, I=1024, top-2 routing.
// R14: R13 (best: 205.3 us) with cvt retiled for LONG READ BURSTS: tile
//      64k x 256c -> each k-row read is 1 KB contiguous (was 256 B @ 8 KB
//      stride); consecutive blocks sweep c0 to extend row spans. LDS
//      transpose as u32 k-pairs, stride 34 dw (2-way banks both sides, free).
//      Router still merged (tail blocks); counts via hipMemsetAsync.
//      GEMMs = R8 verbatim (measured optimum; R9/R10/R12 deviations all lost).
// ---------------------------------------------------------------------------

typedef unsigned short u16;
typedef __attribute__((ext_vector_type(8))) __bf16 bf16x8;
typedef __attribute__((ext_vector_type(4))) float f32x4;

#define T_TOK 1024
#define H_DIM 1024
#define E_NUM 8
#define I_DIM 1024
#define ALPHA 1.702f
#define LIMIT 7.0f

__device__ __forceinline__ u16 f2bf(float f) {
    unsigned u = __builtin_bit_cast(unsigned, f);
    u = (u + 0x7FFFu + ((u >> 16) & 1u)) >> 16;
    return (u16)u;
}

__device__ __forceinline__ unsigned pk2(float lo, float hi) {
#if defined(__has_builtin) && __has_builtin(__builtin_amdgcn_cvt_pk_bf16_f32)
    typedef __attribute__((ext_vector_type(2))) __bf16 bf16x2_t;
    bf16x2_t v = __builtin_amdgcn_cvt_pk_bf16_f32(lo, hi);
    return __builtin_bit_cast(unsigned, v);
#else
    return (unsigned)f2bf(lo) | ((unsigned)f2bf(hi) << 16);
#endif
}

__device__ __forceinline__ f32x4 mfma16(bf16x8 a, bf16x8 b, f32x4 c) {
    return __builtin_amdgcn_mfma_f32_16x16x32_bf16(a, b, c, 0, 0, 0);
}

// async global->LDS, 16B per lane; LDS dest is wave-uniform base + lane*16.
__device__ __forceinline__ void gld16(const void* g, void* l) {
    __builtin_amdgcn_global_load_lds(
        (const __attribute__((address_space(1))) void*)g,
        (__attribute__((address_space(3))) void*)l, 16, 0, 0);
}

__device__ __forceinline__ void expert_range(const int* counts, int e,
                                             int& cnt, int& abase) {
    int a = 0, c = 0;
#pragma unroll
    for (int i = 0; i < E_NUM; ++i) {
        int v = counts[i];
        if (i < e) a += v;
        if (i == e) c = v;
    }
    cnt = c; abase = a;
}

// ---- K0: fused {weight fp32->bf16 transpose} + {router/dispatch} ----------
// cvt blocks 0..1535: tile 64k x 256c. gup: 8e x 128 tiles (c0 fastest) =
// 1024; dp: 8e x 64 = 512. Reads: 1 KB contiguous per k-row (16 rows/iter,
// 4 iters). LDS u32 k-pairs [256c][34] (2-way banks). Writes: one 128 B
// output row per thread. Router blocks 1536..2559: token t = b - 1536.
__global__ __launch_bounds__(256) void k_cvt_router(
    const float* __restrict__ gup, const float* __restrict__ dp,
    u16* __restrict__ gupT, u16* __restrict__ dpT,
    const float* __restrict__ x, const float* __restrict__ rw,
    const float* __restrict__ rb, const float* __restrict__ db,
    int* __restrict__ counts, int* __restrict__ tok_list,
    float* __restrict__ w_list, u16* __restrict__ xb,
    float* __restrict__ out)
{
    __shared__ __align__(16) unsigned shmem32[256 * 34];   // 34816 B
    const int b = blockIdx.x;
    const int tid = threadIdx.x;

    if (b < 1536) {
        // ---------------- cvt path: 64k x 256c ----------------
        const float* src; u16* dst; int C, k0, c0;
        if (b < 1024) {                       // gup: 128 tiles/expert
            int e = b >> 7, t = b & 127;
            c0 = (t & 7) << 8; k0 = (t >> 3) << 6;   // c0 fastest
            src = gup + ((size_t)e << 21); dst = gupT + ((size_t)e << 21); C = 2048;
        } else {                              // dp: 64 tiles/expert
            int b2 = b - 1024;
            int e = b2 >> 6, t = b2 & 63;
            c0 = (t & 3) << 8; k0 = (t >> 2) << 6;
            src = dp + ((size_t)e << 20); dst = dpT + ((size_t)e << 20); C = 1024;
        }
        const int kp = tid >> 5, cg = tid & 31;   // k-pair-of-iter, col-group
#pragma unroll
        for (int iter = 0; iter < 4; ++iter) {
            const int kl = k0 + iter * 16 + kp * 2;
            const float* r0 = src + (size_t)kl * C + c0 + cg * 8;
            const float* r1 = r0 + C;
            float4 a0 = *(const float4*)(r0);
            float4 a1 = *(const float4*)(r0 + 4);
            float4 b0 = *(const float4*)(r1);
            float4 b1 = *(const float4*)(r1 + 4);
            const float* pa0 = (const float*)&a0; const float* pa1 = (const float*)&a1;
            const float* pb0 = (const float*)&b0; const float* pb1 = (const float*)&b1;
            const int kpair = iter * 8 + kp;       // 0..31
#pragma unroll
            for (int i = 0; i < 4; ++i) {
                shmem32[(cg * 8 + i) * 34 + kpair]     = pk2(pa0[i], pb0[i]);
                shmem32[(cg * 8 + 4 + i) * 34 + kpair] = pk2(pa1[i], pb1[i]);
            }
        }
        __syncthreads();
        const int oc = tid;                       // one output row per thread
        const unsigned* lrow = &shmem32[oc * 34];
        u16* orow = dst + (size_t)(c0 + oc) * 1024 + k0;
#pragma unroll
        for (int j = 0; j < 8; ++j) {
            uint2 lo = *(const uint2*)&lrow[j * 4];
            uint2 hi = *(const uint2*)&lrow[j * 4 + 2];
            *(uint4*)(orow + j * 8) = make_uint4(lo.x, lo.y, hi.x, hi.y);
        }
        return;
    }

    // ---------------- router path (R8-proven) ----------------
    const int t = b - 1536;
    float* red = (float*)shmem32;                     // [4][E_NUM]
    int*   se  = (int*)(shmem32 + 64);                // [2]
    float* sw  = (float*)(shmem32 + 66);              // [2]

    const float4 xv = *(const float4*)(x + (size_t)t * H_DIM + tid * 4);
    *(uint2*)(xb + (size_t)t * H_DIM + tid * 4) =
        make_uint2(pk2(xv.x, xv.y), pk2(xv.z, xv.w));

    float p[E_NUM];
#pragma unroll
    for (int e = 0; e < E_NUM; ++e) {
        const float4 wv = *(const float4*)(rw + e * H_DIM + tid * 4);
        p[e] = xv.x * wv.x + xv.y * wv.y + xv.z * wv.z + xv.w * wv.w;
    }
#pragma unroll
    for (int off = 32; off; off >>= 1) {
#pragma unroll
        for (int e = 0; e < E_NUM; ++e) p[e] += __shfl_down(p[e], off, 64);
    }
    const int lane = tid & 63, wvid = tid >> 6;
    if (lane == 0) {
#pragma unroll
        for (int e = 0; e < E_NUM; ++e) red[wvid * E_NUM + e] = p[e];
    }
    __syncthreads();
    if (tid == 0) {
        float lg[E_NUM];
#pragma unroll
        for (int e = 0; e < E_NUM; ++e)
            lg[e] = red[0 * E_NUM + e] + red[1 * E_NUM + e] +
                    red[2 * E_NUM + e] + red[3 * E_NUM + e] + rb[e];
        float m1 = -1e30f, m2 = -1e30f; int i1 = 0, i2 = 0;
#pragma unroll
        for (int e = 0; e < E_NUM; ++e) {
            float l = lg[e];
            if (l > m1) { m2 = m1; i2 = i1; m1 = l; i1 = e; }
            else if (l > m2) { m2 = l; i2 = e; }
        }
        float s = 0.f;
#pragma unroll
        for (int e = 0; e < E_NUM; ++e) s += __expf(lg[e] - m1);
        const float w0 = 1.0f / s;
        const float w1 = __expf(m2 - m1) / s;
        int slot0 = atomicAdd(&counts[i1], 1);
        tok_list[i1 * T_TOK + slot0] = t;
        w_list[i1 * T_TOK + slot0] = w0;
        int slot1 = atomicAdd(&counts[i2], 1);
        tok_list[i2 * T_TOK + slot1] = t;
        w_list[i2 * T_TOK + slot1] = w1;
        se[0] = i1; se[1] = i2; sw[0] = w0; sw[1] = w1;
    }
    __syncthreads();
    const int e0 = se[0], e1 = se[1];
    const float w0 = sw[0], w1 = sw[1];
    const int c = tid * 4;
    float4 d0 = *(const float4*)(db + e0 * H_DIM + c);
    float4 d1 = *(const float4*)(db + e1 * H_DIM + c);
    float4 o;
    o.x = w0 * d0.x + w1 * d1.x;
    o.y = w0 * d0.y + w1 * d1.y;
    o.z = w0 * d0.z + w1 * d1.z;
    o.w = w0 * d0.w + w1 * d1.w;
    *(float4*)(out + (size_t)t * H_DIM + c) = o;
}

// --------------------------- K2: gate_up GEMM + GLU -------------------------
// tile 64 rows x 128 outputs (64g+64u), BK=64, 16 phases, 3-buffer counted
// vmcnt pipeline (stage 2 ahead, NL=6), XOR-swizzled LDS. 72 KB -> 2 blk/CU.
__global__ __launch_bounds__(256, 2) void k_gateup(
    const u16* __restrict__ gupT, const float* __restrict__ gub,
    const int* __restrict__ counts, const int* __restrict__ tok_list,
    const u16* __restrict__ xb, u16* __restrict__ act)
{
    const int e = blockIdx.z;
    int cnt, abase;
    expert_range(counts, e, cnt, abase);
    const int m0 = blockIdx.y * 64;
    if (m0 >= cnt) return;
    const int n0 = blockIdx.x * 64;            // gate cols n0.., up cols 1024+n0..
    const int tid = threadIdx.x;
    const int lane = tid & 63, wv = tid >> 6;
    const int fm = lane & 15, kg = lane >> 4;
    const int wm = wv >> 1, wn = wv & 1;

    __shared__ __align__(16) u16 As0[64 * 64], As1[64 * 64], As2[64 * 64];
    __shared__ __align__(16) u16 Bs0[128 * 64], Bs1[128 * 64], Bs2[128 * 64];
    u16* const AB[3] = {As0, As1, As2};
    u16* const BB[3] = {Bs0, Bs1, Bs2};

    // staging: wave writes 1KB chunks; lane l -> row chunk+ (l>>3), slot l&7.
    // Pre-swizzle the GLOBAL source slot by ^row (linear dest, swizzled read).
    const int lr = lane >> 3;
    const int lk = ((lane & 7) ^ lr) * 8;      // swizzled 16B-slot, in u16
    const u16* gA[2];
#pragma unroll
    for (int i = 0; i < 2; ++i) {
        int row = (wv * 2 + i) * 8 + lr;
        int slot = m0 + row;
        int tok = (slot < cnt) ? tok_list[e * T_TOK + slot] : 0;
        gA[i] = xb + (size_t)tok * H_DIM + lk;
    }
    const u16* gB[4];
#pragma unroll
    for (int i = 0; i < 4; ++i) {
        int row = (wv * 4 + i) * 8 + lr;       // 0..127
        int col = (row < 64) ? (n0 + row) : (1024 + n0 + row - 64);
        gB[i] = gupT + ((size_t)e << 21) + (size_t)col * 1024 + lk;
    }

    f32x4 accg[2][2], accu[2][2];
#pragma unroll
    for (int m = 0; m < 2; ++m)
#pragma unroll
        for (int n = 0; n < 2; ++n) {
            accg[m][n] = (f32x4){0.f, 0.f, 0.f, 0.f};
            accu[m][n] = (f32x4){0.f, 0.f, 0.f, 0.f};
        }

#define GU_STAGE(AS, BS, KB)                                                   \
    {                                                                          \
        gld16(gA[0] + (KB), (u16*)(AS) + (wv * 2 + 0) * 512);                  \
        gld16(gA[1] + (KB), (u16*)(AS) + (wv * 2 + 1) * 512);                  \
        gld16(gB[0] + (KB), (u16*)(BS) + (wv * 4 + 0) * 512);                  \
        gld16(gB[1] + (KB), (u16*)(BS) + (wv * 4 + 1) * 512);                  \
        gld16(gB[2] + (KB), (u16*)(BS) + (wv * 4 + 2) * 512);                  \
        gld16(gB[3] + (KB), (u16*)(BS) + (wv * 4 + 3) * 512);                  \
    }
    // read offset: all A/B rows have row&7 == fm&7 -> same swizzled k-offset
#define GU_MFMA(AS, BS)                                                        \
    {                                                                          \
        _Pragma("unroll")                                                      \
        for (int ks = 0; ks < 2; ++ks) {                                       \
            const int ko = (((ks * 4 + kg) ^ (fm & 7)) << 3);                  \
            bf16x8 a0 = *(const bf16x8*)((const u16*)(AS) + (wm * 32 + fm) * 64 + ko);        \
            bf16x8 a1 = *(const bf16x8*)((const u16*)(AS) + (wm * 32 + 16 + fm) * 64 + ko);   \
            bf16x8 bg0 = *(const bf16x8*)((const u16*)(BS) + (wn * 32 + fm) * 64 + ko);       \
            bf16x8 bg1 = *(const bf16x8*)((const u16*)(BS) + (wn * 32 + 16 + fm) * 64 + ko);  \
            bf16x8 bu0 = *(const bf16x8*)((const u16*)(BS) + (64 + wn * 32 + fm) * 64 + ko);  \
            bf16x8 bu1 = *(const bf16x8*)((const u16*)(BS) + (64 + wn * 32 + 16 + fm) * 64 + ko); \
            accg[0][0] = mfma16(a0, bg0, accg[0][0]);                          \
            accg[0][1] = mfma16(a0, bg1, accg[0][1]);                          \
            accu[0][0] = mfma16(a0, bu0, accu[0][0]);                          \
            accu[0][1] = mfma16(a0, bu1, accu[0][1]);                          \
            accg[1][0] = mfma16(a1, bg0, accg[1][0]);                          \
            accg[1][1] = mfma16(a1, bg1, accg[1][1]);                          \
            accu[1][0] = mfma16(a1, bu0, accu[1][0]);                          \
            accu[1][1] = mfma16(a1, bu1, accu[1][1]);                          \
        }                                                                      \
    }

    GU_STAGE(AB[0], BB[0], 0);
    GU_STAGE(AB[1], BB[1], 64);
#pragma unroll
    for (int p = 0; p < 16; ++p) {
        // certify stage p landed (only stage p+1's 6 loads may remain);
        // lgkmcnt(0): all ds_reads of prior phase done before buffers reused.
        if (p == 15) { asm volatile("s_waitcnt vmcnt(0) lgkmcnt(0)" ::: "memory"); }
        else         { asm volatile("s_waitcnt vmcnt(6) lgkmcnt(0)" ::: "memory"); }
        __builtin_amdgcn_s_barrier();
        if (p + 2 < 16) GU_STAGE(AB[(p + 2) % 3], BB[(p + 2) % 3], (p + 2) * 64);
        GU_MFMA(AB[p % 3], BB[p % 3]);
    }
#undef GU_STAGE
#undef GU_MFMA

    // epilogue: bias + clamped GLU -> compact bf16 act rows
#pragma unroll
    for (int m = 0; m < 2; ++m) {
#pragma unroll
        for (int r = 0; r < 4; ++r) {
            int row = wm * 32 + m * 16 + kg * 4 + r;   // C/D: row=(lane>>4)*4+reg
            int slot = m0 + row;
            if (slot >= cnt) continue;
            size_t arow = (size_t)(abase + slot) * I_DIM;
#pragma unroll
            for (int n = 0; n < 2; ++n) {
                int cn = n0 + wn * 32 + n * 16 + fm;   // C/D: col=lane&15
                float g = accg[m][n][r] + gub[e * 2048 + cn];
                float u = accu[m][n][r] + gub[e * 2048 + 1024 + cn];
                g = fminf(g, LIMIT);
                u = fminf(fmaxf(u, -LIMIT), LIMIT);
                float glu = g / (1.f + __expf(-ALPHA * g));
                act[arow + cn] = f2bf((u + 1.f) * glu);
            }
        }
    }
}

// ---------------- K3: down GEMM * w, atomic combine into out ----------------
// tile 64x64, K=1024, 16 phases, 3-buffer counted vmcnt (NL=4), swizzled LDS.
// 48 KB -> 3 blk/CU.
__global__ __launch_bounds__(256, 3) void k_down(
    const u16* __restrict__ dpT,
    const int* __restrict__ counts, const int* __restrict__ tok_list,
    const float* __restrict__ w_list,
    const u16* __restrict__ act, float* __restrict__ out)
{
    const int e = blockIdx.z;
    int cnt, abase;
    expert_range(counts, e, cnt, abase);
    const int m0 = blockIdx.y * 64;
    if (m0 >= cnt) return;
    const int n0 = blockIdx.x * 64;
    const int tid = threadIdx.x;
    const int lane = tid & 63, wv = tid >> 6;
    const int fm = lane & 15, kg = lane >> 4;
    const int wm = wv >> 1, wn = wv & 1;

    __shared__ __align__(16) u16 As0[64 * 64], As1[64 * 64], As2[64 * 64];
    __shared__ __align__(16) u16 Bs0[64 * 64], Bs1[64 * 64], Bs2[64 * 64];
    u16* const AB[3] = {As0, As1, As2};
    u16* const BB[3] = {Bs0, Bs1, Bs2};

    const int lr = lane >> 3;
    const int lk = ((lane & 7) ^ lr) * 8;      // pre-swizzled source slot
    const u16* gA[2];
    const u16* gB[2];
#pragma unroll
    for (int i = 0; i < 2; ++i) {
        int row = (wv * 2 + i) * 8 + lr;
        gA[i] = act + (size_t)(abase + m0 + row) * I_DIM + lk;
        gB[i] = dpT + ((size_t)e << 20) + (size_t)(n0 + row) * 1024 + lk;
    }

    f32x4 acc[2][2];
#pragma unroll
    for (int m = 0; m < 2; ++m)
#pragma unroll
        for (int n = 0; n < 2; ++n) acc[m][n] = (f32x4){0.f, 0.f, 0.f, 0.f};

#define DN_STAGE(AS, BS, KB)                                                   \
    {                                                                          \
        gld16(gA[0] + (KB), (u16*)(AS) + (wv * 2 + 0) * 512);                  \
        gld16(gA[1] + (KB), (u16*)(AS) + (wv * 2 + 1) * 512);                  \
        gld16(gB[0] + (KB), (u16*)(BS) + (wv * 2 + 0) * 512);                  \
        gld16(gB[1] + (KB), (u16*)(BS) + (wv * 2 + 1) * 512);                  \
    }
#define DN_MFMA(AS, BS)                                                        \
    {                                                                          \
        _Pragma("unroll")                                                      \
        for (int ks = 0; ks < 2; ++ks) {                                       \
            const int ko = (((ks * 4 + kg) ^ (fm & 7)) << 3);                  \
            bf16x8 a0 = *(const bf16x8*)((const u16*)(AS) + (wm * 32 + fm) * 64 + ko);      \
            bf16x8 a1 = *(const bf16x8*)((const u16*)(AS) + (wm * 32 + 16 + fm) * 64 + ko); \
            bf16x8 b0 = *(const bf16x8*)((const u16*)(BS) + (wn * 32 + fm) * 64 + ko);      \
            bf16x8 b1 = *(const bf16x8*)((const u16*)(BS) + (wn * 32 + 16 + fm) * 64 + ko); \
            acc[0][0] = mfma16(a0, b0, acc[0][0]);                             \
            acc[0][1] = mfma16(a0, b1, acc[0][1]);                             \
            acc[1][0] = mfma16(a1, b0, acc[1][0]);                             \
            acc[1][1] = mfma16(a1, b1, acc[1][1]);                             \
        }                                                                      \
    }

    DN_STAGE(AB[0], BB[0], 0);
    DN_STAGE(AB[1], BB[1], 64);
#pragma unroll
    for (int p = 0; p < 16; ++p) {
        if (p == 15) { asm volatile("s_waitcnt vmcnt(0) lgkmcnt(0)" ::: "memory"); }
        else         { asm volatile("s_waitcnt vmcnt(4) lgkmcnt(0)" ::: "memory"); }
        __builtin_amdgcn_s_barrier();
        if (p + 2 < 16) DN_STAGE(AB[(p + 2) % 3], BB[(p + 2) % 3], (p + 2) * 64);
        DN_MFMA(AB[p % 3], BB[p % 3]);
    }
#undef DN_STAGE
#undef DN_MFMA

#pragma unroll
    for (int m = 0; m < 2; ++m) {
#pragma unroll
        for (int r = 0; r < 4; ++r) {
            int row = wm * 32 + m * 16 + kg * 4 + r;
            int slot = m0 + row;
            if (slot >= cnt) continue;
            float wgt = w_list[e * T_TOK + slot];
            int tok = tok_list[e * T_TOK + slot];
            float* orow = out + (size_t)tok * H_DIM;
#pragma unroll
            for (int n = 0; n < 2; ++n) {
                int col = n0 + wn * 32 + n * 16 + fm;
                atomicAdd(orow + col, acc[m][n][r] * wgt);
            }
        }
    }
}

// ---------------------------------------------------------------------------
extern "C" void kernel_launch(void* const* d_in, const int* in_sizes, int n_in,
                              void* d_out, int out_size, void* d_ws, size_t ws_size,
                              hipStream_t stream) {
    const float* x   = (const float*)d_in[0]; // [1,1024,1024]
    const float* rw  = (const float*)d_in[1]; // [8,1024]
    const float* rb  = (const float*)d_in[2]; // [8]
    const float* gup = (const float*)d_in[3]; // [8,1024,2048]
    const float* gub = (const float*)d_in[4]; // [8,2048]
    const float* dp  = (const float*)d_in[5]; // [8,1024,1024]
    const float* db  = (const float*)d_in[6]; // [8,1024]
    float* out = (float*)d_out;

    char* ws = (char*)d_ws;
    int*   counts   = (int*)(ws);                    // 8 ints
    int*   tok_list = (int*)(ws + 64);               // 8*1024 ints (32 KB)
    float* w_list   = (float*)(ws + 64 + 32768);     // 8*1024 f32  (32 KB)
    u16*   xb       = (u16*)(ws + 65600);            // 1024*1024 bf16 (2 MB)
    u16*   act      = (u16*)(ws + 65600 + 2097152);  // 2112 rows bf16 (+slack)
    u16*   gupT     = (u16*)(ws + 8388608);          // [8][2048][1024] bf16 (32 MB)
    u16*   dpT      = (u16*)(ws + 41943040);         // [8][1024][1024] bf16 (16 MB)

    hipMemsetAsync(counts, 0, E_NUM * sizeof(int), stream);
    k_cvt_router<<<1536 + T_TOK, 256, 0, stream>>>(gup, dp, gupT, dpT,
                                                   x, rw, rb, db, counts,
                                                   tok_list, w_list, xb, out);
    k_gateup<<<dim3(16, 16, 8), 256, 0, stream>>>(gupT, gub, counts, tok_list,
                                                  xb, act);
    k_down<<<dim3(16, 16, 8), 256, 0, stream>>>(dpT, counts, tok_list, w_list,
                                                act, out);
}